// Round 20
// baseline (419.237 us; speedup 1.0000x reference)
//
#include <hip/hip_runtime.h>

#define NB 8192
#define NT 1024
#define NH 10
#define ROWS_PER_WAVE 4     // 10 lanes/row, lanes 40..63 idle
#define ROWS_PER_BLOCK 16   // 4 waves/block

typedef float v2f __attribute__((ext_vector_type(2)));
typedef float v4f __attribute__((ext_vector_type(4)));

#define LOG2E 1.44269504088896340736f

__device__ __forceinline__ float rcpf(float x) { return __builtin_amdgcn_rcpf(x); }
__device__ __forceinline__ float exp2i(float x) {
#if __has_builtin(__builtin_amdgcn_exp2f)
    return __builtin_amdgcn_exp2f(x);   // scheduler-friendly v_exp_f32
#else
    float r;
    asm("v_exp_f32 %0, %1" : "=v"(r) : "v"(x));
    return r;
#endif
}
// u accumulated with 2*log2e pre-scaled weights: tanh = 1 - 2/(2^u + 1)
__device__ __forceinline__ float tanh2u(float u) { return fmaf(-2.0f, rcpf(exp2i(u) + 1.0f), 1.0f); }
// paired sigmoid, ONE rcp: sa=1/(1+2^qa), sb=1/(1+2^qb); da,db in [1,2^30] -> product finite
__device__ __forceinline__ void sigm2q2(float qa, float qb, float& sa, float& sb) {
    const float da = 1.0f + exp2i(qa);
    const float db = 1.0f + exp2i(qb);
    const float R = rcpf(da * db);
    sa = db * R;
    sb = da * R;
}

__device__ __forceinline__ v2f lo2(v4f a) { return __builtin_shufflevector(a, a, 0, 1); }
__device__ __forceinline__ v2f hi2(v4f a) { return __builtin_shufflevector(a, a, 2, 3); }
__device__ __forceinline__ v2f pkfma(v2f a, v2f b, v2f c) {  // -> v_pk_fma_f32
    return __builtin_elementwise_fma(a, b, c);
}

// Row of 10 weights as 5 v2f pairs (pk_fma operands).
struct W5 { v2f p[5]; };
__device__ __forceinline__ W5 loadrow_scaled(const float* __restrict__ q, float s) {
    W5 w;
#pragma unroll
    for (int k = 0; k < 5; ++k) w.p[k] = (v2f){q[2 * k] * s, q[2 * k + 1] * s};
    return w;
}
// acc += w . h   (5 pk_fma into a v2f acc; caller hsums)
__device__ __forceinline__ v2f dotWacc(const W5& w, v4f ha, v4f hb, v2f hc, v2f acc) {
    acc = pkfma(w.p[0], lo2(ha), acc);
    acc = pkfma(w.p[1], hi2(ha), acc);
    acc = pkfma(w.p[2], lo2(hb), acc);
    acc = pkfma(w.p[3], hi2(hb), acc);
    acc = pkfma(w.p[4], hc, acc);
    return acc;
}
__device__ __forceinline__ float hsum(v2f a) { return a.x + a.y; }

__global__ __launch_bounds__(256) void gru_fused(
    const float* __restrict__ X,
    const float* __restrict__ Wih0, const float* __restrict__ Whh0,
    const float* __restrict__ bih0, const float* __restrict__ bhh0,
    const float* __restrict__ Wih1, const float* __restrict__ Whh1,
    const float* __restrict__ bih1, const float* __restrict__ bhh1,
    const float* __restrict__ Wfc,  const float* __restrict__ bfc,
    float* __restrict__ out)
{
    // Broadcast buffer (R10 layout, read-conflict-free; writes <=2-way = ~1 cyc).
    __shared__ __align__(16) float hls[4][2][5][12];

    const int tid  = threadIdx.x;
    const int lane = tid & 63;
    const int wave = tid >> 6;
    const int g    = lane / 10;      // 0..3 real, 4..6 idle
    const int j    = lane - g * 10;  // 0..9
    const int gg   = (g < 4) ? g : 4;  // idle lanes use dump row 4

    const bool active = (g < ROWS_PER_WAVE);
    int b = blockIdx.x * ROWS_PER_BLOCK + wave * ROWS_PER_WAVE + (active ? g : 0);
    const bool store_ok = active && (b < NB);
    if (b >= NB) b = NB - 1;

    const int r0 = j, r1 = j + 10, r2 = j + 20;
    const float Sz = -LOG2E;         // r,z rows: sigmoid in log2 domain
    const float Sn = 2.0f * LOG2E;   // n rows: tanh in log2 domain

    // ---- per-lane weights, pre-scaled into the log2 domain ----
    const v2f wxr = (v2f){Wih0[r0 * 2] * Sz, Wih0[r0 * 2 + 1] * Sz};
    const v2f wxz = (v2f){Wih0[r1 * 2] * Sz, Wih0[r1 * 2 + 1] * Sz};
    const v2f wxn = (v2f){Wih0[r2 * 2] * Sn, Wih0[r2 * 2 + 1] * Sn};

    const W5 whr0 = loadrow_scaled(Whh0 + r0 * NH, Sz);
    const W5 whz0 = loadrow_scaled(Whh0 + r1 * NH, Sz);
    const W5 whn0 = loadrow_scaled(Whh0 + r2 * NH, Sn);
    const W5 wir1 = loadrow_scaled(Wih1 + r0 * NH, Sz);
    const W5 wiz1 = loadrow_scaled(Wih1 + r1 * NH, Sz);
    const W5 win1 = loadrow_scaled(Wih1 + r2 * NH, Sn);
    const W5 whr1 = loadrow_scaled(Whh1 + r0 * NH, Sz);
    const W5 whz1 = loadrow_scaled(Whh1 + r1 * NH, Sz);
    const W5 whn1 = loadrow_scaled(Whh1 + r2 * NH, Sn);

    // hoisted gate-bias seed vectors (loop-invariant)
    const v2f sr0 = (v2f){(bih0[r0] + bhh0[r0]) * Sz, 0.0f};
    const v2f sz0 = (v2f){(bih0[r1] + bhh0[r1]) * Sz, 0.0f};
    const v2f sx0 = (v2f){bih0[r2] * Sn, 0.0f};
    const v2f sh0 = (v2f){bhh0[r2] * Sn, 0.0f};
    const v2f sr1 = (v2f){(bih1[r0] + bhh1[r0]) * Sz, 0.0f};
    const v2f sz1 = (v2f){(bih1[r1] + bhh1[r1]) * Sz, 0.0f};
    const v2f sx1 = (v2f){bih1[r2] * Sn, 0.0f};
    const v2f sh1 = (v2f){bhh1[r2] * Sn, 0.0f};

    float* const L0 = &hls[wave][0][gg][0];
    float* const L1 = &hls[wave][1][gg][0];

    // Pipeline state (iteration i of the main loop):
    //   acc*   = L0 dot accumulators for step i      (computed in iter i-1)
    //   h0 regs = h0(i-1) ; h1 regs <- nh1 = h1(i-2) ; my0 = h0-own(i-1), my1 = h1-own(i-2)
    v4f h0a = (v4f){0,0,0,0}, h0b = (v4f){0,0,0,0}; v2f h0c = (v2f){0,0};
    v4f h1a, h1b; v2f h1c;
    v4f nh1a = (v4f){0,0,0,0}, nh1b = (v4f){0,0,0,0}; v2f nh1c = (v2f){0,0};
    float my0 = 0.0f, my1 = 0.0f;

    const float2* xp = reinterpret_cast<const float2*>(X) + (size_t)b * NT;

    v2f accr, accz, accx, acch, aqr, aqz, aqx, aqh;
    v4f nh0a, nh0b; v2f nh0c;
    float r0v, z0v, n0v, r1v, z1v, n1v;
    float2 xc, xn2;

    // finalize L0 step from acc*: trans chain -> my0 -> write + issue h0 reads
#define L0_FINAL()                                                              \
    sigm2q2(hsum(accr), hsum(accz), r0v, z0v);                                  \
    n0v = tanh2u(fmaf(r0v, hsum(acch), hsum(accx)));                            \
    my0 = fmaf(z0v, my0 - n0v, n0v);                                            \
    L0[j] = my0;                                                                \
    nh0a = *reinterpret_cast<const v4f*>(L0);                                   \
    nh0b = *reinterpret_cast<const v4f*>(L0 + 4);                               \
    nh0c = *reinterpret_cast<const v2f*>(L0 + 8)

    // L0 dot accumulators for the NEXT step, from current h0 regs + x
#define L0_DOTS(xv)                                                             \
    accr = pkfma(wxr, xv, sr0);                                                 \
    accz = pkfma(wxz, xv, sz0);                                                 \
    accx = pkfma(wxn, xv, sx0);                                                 \
    accr = dotWacc(whr0, h0a, h0b, h0c, accr);                                  \
    accz = dotWacc(whz0, h0a, h0b, h0c, accz);                                  \
    acch = dotWacc(whn0, h0a, h0b, h0c, sh0)

    // L1 dots (h1 part + h0 part) for the step whose h0 is in regs
#define L1_DOTS()                                                               \
    aqr = dotWacc(whr1, h1a, h1b, h1c, sr1);                                    \
    aqz = dotWacc(whz1, h1a, h1b, h1c, sz1);                                    \
    aqh = dotWacc(whn1, h1a, h1b, h1c, sh1);                                    \
    aqr = dotWacc(wir1, h0a, h0b, h0c, aqr);                                    \
    aqz = dotWacc(wiz1, h0a, h0b, h0c, aqz);                                    \
    aqx = dotWacc(win1, h0a, h0b, h0c, sx1)

#define L1_FINAL()                                                              \
    sigm2q2(hsum(aqr), hsum(aqz), r1v, z1v);                                    \
    n1v = tanh2u(fmaf(r1v, hsum(aqh), hsum(aqx)));                              \
    my1 = fmaf(z1v, my1 - n1v, n1v);                                            \
    L1[j] = my1;                                                                \
    nh1a = *reinterpret_cast<const v4f*>(L1);                                   \
    nh1b = *reinterpret_cast<const v4f*>(L1 + 4);                               \
    nh1c = *reinterpret_cast<const v2f*>(L1 + 8)

    // -------- prologue: seed acc*(0) (h0(-1)=0 -> input side only); peel i=0 --------
    {
        xc = xp[0];
        const v2f xv0 = (v2f){xc.x, xc.y};
        accr = pkfma(wxr, xv0, sr0);
        accz = pkfma(wxz, xv0, sz0);
        accx = pkfma(wxn, xv0, sx0);
        acch = sh0;
        xc = xp[1];
        L0_FINAL();                              // my0(0); write; issue h0(0) reads
        h0a = nh0a; h0b = nh0b; h0c = nh0c;      // h0(0)  (one-time exposed RT)
        const v2f xv1 = (v2f){xc.x, xc.y};
        L0_DOTS(xv1);                            // acc*(1)
        xc = xp[2];                              // x(2)
    }

    // -------- main loop: iter i does L0-final(i), L1(i-1), L0-dots(i+1) --------
    for (int i = 1; i <= NT - 2; ++i) {
        xn2 = xp[(i + 2 <= NT - 1) ? (i + 2) : (NT - 1)];
        L0_FINAL();                              // trans chain (i) ...
        h1a = nh1a; h1b = nh1b; h1c = nh1c;      // h1(i-2)
        L1_DOTS();                               // ... filled by 30 indep pk_fma
        L1_FINAL();                              // trans chain (i-1) ...
        h0a = nh0a; h0b = nh0b; h0c = nh0c;      // h0(i)  (RT covered by L1)
        const v2f xv = (v2f){xc.x, xc.y};        // x(i+1)
        L0_DOTS(xv);                             // ... filled by 18 indep pk_fma
        xc = xn2;
    }

    // -------- peel i = NT-1 --------
    {
        L0_FINAL();                              // my0(NT-1); issue h0(NT-1) reads
        h1a = nh1a; h1b = nh1b; h1c = nh1c;      // h1(NT-3)
        L1_DOTS();                               // step NT-2 (h0(NT-2) in regs)
        L1_FINAL();                              // my1(NT-2); issue h1(NT-2) reads
        h0a = nh0a; h0b = nh0b; h0c = nh0c;      // h0(NT-1)
    }
    // -------- epilogue: L1 step NT-1 --------
    {
        h1a = nh1a; h1b = nh1b; h1c = nh1c;      // h1(NT-2)
        L1_DOTS();                               // h0(NT-1) + h1(NT-2)
        L1_FINAL();                              // my1(NT-1); write; issue reads
        h1a = nh1a; h1b = nh1b; h1c = nh1c;      // h1(NT-1) for FC
    }
#undef L0_FINAL
#undef L0_DOTS
#undef L1_DOTS
#undef L1_FINAL

    // ---- FC head ----
    if (store_ok && j < 2) {
        const W5 wf = loadrow_scaled(Wfc + j * NH, 1.0f);
        out[(size_t)b * 2 + j] = hsum(dotWacc(wf, h1a, h1b, h1c, (v2f){bfc[j], 0.0f}));
    }
}

extern "C" void kernel_launch(void* const* d_in, const int* in_sizes, int n_in,
                              void* d_out, int out_size, void* d_ws, size_t ws_size,
                              hipStream_t stream) {
    const float* X    = (const float*)d_in[0];
    const float* Wih0 = (const float*)d_in[1];
    const float* Whh0 = (const float*)d_in[2];
    const float* bih0 = (const float*)d_in[3];
    const float* bhh0 = (const float*)d_in[4];
    const float* Wih1 = (const float*)d_in[5];
    const float* Whh1 = (const float*)d_in[6];
    const float* bih1 = (const float*)d_in[7];
    const float* bhh1 = (const float*)d_in[8];
    const float* Wfc  = (const float*)d_in[9];
    const float* bfc  = (const float*)d_in[10];
    float* out = (float*)d_out;

    const int grid = NB / ROWS_PER_BLOCK;  // 512 blocks -> 2048 waves = 2/SIMD
    gru_fused<<<grid, 256, 0, stream>>>(X, Wih0, Whh0, bih0, bhh0,
                                        Wih1, Whh1, bih1, bhh1, Wfc, bfc, out);
}